// Round 14
// baseline (341.365 us; speedup 1.0000x reference)
//
#include <hip/hip_runtime.h>
#include <hip/hip_bf16.h>

#define SEQ_T 784
#define HID   128
#define S_H   160   // bf16 h-plane stride (shorts): exact 2-way bank tiling = free (R11)
#define S_Q   160   // i8 h-plane stride (bytes)

typedef __attribute__((ext_vector_type(8))) short  short8;
typedef __attribute__((ext_vector_type(4))) int    intx4;
typedef __attribute__((ext_vector_type(4))) float  floatx4;
typedef __attribute__((ext_vector_type(8))) float  float8;

static __device__ __forceinline__ short bf16_of(float f) {
  union { float f; unsigned u; } v; v.f = f;
  return (short)((v.u + 0x7fffu + ((v.u >> 16) & 1u)) >> 16);
}

// v_exp_f32 computes 2^x natively; log2e factors are folded into constants
static __device__ __forceinline__ float exp2f_hw(float x) {
  return __builtin_amdgcn_exp2f(x);
}

#define MFMA_BF16 __builtin_amdgcn_mfma_f32_16x16x32_bf16
#define MFMA_I8   __builtin_amdgcn_mfma_i32_16x16x64_i8

// 256 blocks x 4 batch rows (1 block/CU). Batch row r at A-row 4r; C reg 0 of
// lane(quad,nn) = batch row quad, column j (R5 probe-verified).
// Hybrid gates: r,z via i8 MFMA (exact i32 accum; R12 absmax 4.88e-4), n bf16.
// R14 = R13 with the __exp2f -> __builtin_amdgcn_exp2f fix:
//  - exp2-domain folding: gate constants and n-gate MFMA weights pre-scaled by
//    -log2e / 2log2e -> v_exp_f32 consumed directly; i8 dequant folded into fma
//  - accumulator zero-init hoisted (persistent zero C-operands)
//  - i8 reads + MFMAs issued first (r-path: MFMA -> sigmoid -> feeds pn chain)
extern "C" __global__ void __launch_bounds__(512, 2)
gru_hyb2(const float* __restrict__ x,    // [1024][784] fp32
         const float* __restrict__ Wi,   // [384]
         const float* __restrict__ bi,   // [384]
         const float* __restrict__ Wh,   // [384][128]
         const float* __restrict__ bh,   // [384]
         const float* __restrict__ Wfc,  // [10][128]
         const float* __restrict__ bfc,  // [10]
         float* __restrict__ out)        // [1024][10] fp32
{
  const int tid  = threadIdx.x;
  const int wv   = tid >> 6;
  const int lane = tid & 63;
  const int quad = lane >> 4;
  const int nn   = lane & 15;
  const int j    = (wv << 4) | nn;   // this lane's hidden column
  const int b0   = blockIdx.x * 4;   // 4 batch rows per block

  __shared__ __align__(16) float xs[SEQ_T][4];          // x fp32, [t][row]
  __shared__ __align__(16) short hb[2][4 * S_H];        // h bf16 (n-gate A), dbuf
  __shared__ __align__(16) signed char hq[2][4 * S_Q];  // h i8 (r,z-gate A), dbuf
  __shared__ float hfin[4][HID];

  for (int i = tid; i < 2 * 4 * S_H; i += 512) ((short*)hb)[i] = 0;
  for (int i = tid; i < 2 * 4 * S_Q; i += 512) ((signed char*)hq)[i] = 0;
  for (int i = tid; i < 4 * SEQ_T; i += 512) {
    const int r = i / SEQ_T;
    const int t = i - r * SEQ_T;
    xs[t][r] = x[(size_t)(b0 + r) * SEQ_T + t];
  }

  const float LOG2E = 1.4426950408889634f;

  // exp2-domain gate constants:
  // sigmoid(p) = 1/(1+exp2(-log2e*p));  tanh(p) = 1 - 2/(1+exp2(2*log2e*p))
  const float wi_r2 = -LOG2E * Wi[j];
  const float wi_z2 = -LOG2E * Wi[HID + j];
  const float c_r2  = -LOG2E * (bi[j] + bh[j]);
  const float c_z2  = -LOG2E * (bi[HID + j] + bh[HID + j]);
  const float win2  = 2.0f * LOG2E * Wi[2 * HID + j];
  const float bin2  = 2.0f * LOG2E * bi[2 * HID + j];
  const float bhn2  = 2.0f * LOG2E * bh[2 * HID + j];

  // i8 B-fragments for r,z: B[k = 64c + quad*16 + e][n = nn] = rn(Wh[g*128+j][k]*s_w)
  const float s_w = 1436.8394f;                 // 127 * sqrt(128)
  const float dq  = -LOG2E * 5.480085e-6f;      // -log2e / (127 * s_w): dequant+domain fold
  intx4 wq[2][2];
  #pragma unroll
  for (int g = 0; g < 2; ++g) {
    const float* wrow = Wh + (size_t)(g * HID + j) * HID;
    #pragma unroll
    for (int c = 0; c < 2; ++c) {
      union { signed char b[16]; intx4 v; } u;
      #pragma unroll
      for (int e = 0; e < 16; ++e)
        u.b[e] = (signed char)__float2int_rn(wrow[c * 64 + quad * 16 + e] * s_w);
      wq[g][c] = u.v;
    }
  }
  // bf16 B-fragments for n, pre-scaled by 2*log2e (values ~0.25, bf16-safe):
  short8 whn[4];
  {
    const float* wrow = Wh + (size_t)(2 * HID + j) * HID;
    #pragma unroll
    for (int kk = 0; kk < 4; ++kk) {
      float8 w = *(const float8*)(wrow + kk * 32 + quad * 8);
      short8 hi;
      #pragma unroll
      for (int e = 0; e < 8; ++e) hi[e] = bf16_of(w[e] * (2.0f * LOG2E));
      whn[kk] = hi;
    }
  }

  float h = 0.0f;                           // h[batch=quad][j], fp32 carry
  const bool aact   = ((nn & 3) == 0);      // lanes carrying real A-rows
  const int  a_off  = (nn >> 2) * S_H + quad * 8;   // bf16 plane (shorts)
  const int  aq_off = (nn >> 2) * S_Q + quad * 16;  // i8 plane (bytes)
  const int  w_off  = quad * S_H + j;
  const int  wq_off = quad * S_Q + j;

  // persistent A-fragments + persistent zero C-operands (no per-step movs)
  const short8 z8 = {0, 0, 0, 0, 0, 0, 0, 0};
  short8 ah[4] = {z8, z8, z8, z8};
  intx4  ai[2] = {{0,0,0,0}, {0,0,0,0}};
  const intx4   iz = {0, 0, 0, 0};
  const floatx4 fz = {0.f, 0.f, 0.f, 0.f};

  __syncthreads();

  auto step = [&](const short* __restrict__ hc, const signed char* __restrict__ qc,
                  short* __restrict__ nx, signed char* __restrict__ nq, int t) {
    if (aact) {                    // EXEC-masked: 16 lanes; i8 first (longest path)
      ai[0] = *(const intx4*)(qc + aq_off);
      ai[1] = *(const intx4*)(qc + aq_off + 64);
      ah[0] = *(const short8*)(hc + a_off);
      ah[1] = *(const short8*)(hc + a_off + 32);
      ah[2] = *(const short8*)(hc + a_off + 64);
      ah[3] = *(const short8*)(hc + a_off + 96);
    }
    const float xt = xs[t][quad];

    // r,z: i8 chains first (feed sigmoids, which gate the n-path)
    intx4 cr = MFMA_I8(ai[0], wq[0][0], iz, 0, 0, 0);
    intx4 cz = MFMA_I8(ai[0], wq[1][0], iz, 0, 0, 0);
    cr = MFMA_I8(ai[1], wq[0][1], cr, 0, 0, 0);
    cz = MFMA_I8(ai[1], wq[1][1], cz, 0, 0, 0);

    // n: bf16 (weights pre-scaled by 2log2e), two independent depth-2 chains
    floatx4 n0 = MFMA_BF16(ah[0], whn[0], fz, 0, 0, 0);
    floatx4 n1 = MFMA_BF16(ah[1], whn[1], fz, 0, 0, 0);
    n0 = MFMA_BF16(ah[2], whn[2], n0, 0, 0, 0);
    n1 = MFMA_BF16(ah[3], whn[3], n1, 0, 0, 0);

    // C reg 0 = batch row quad, column j. Full wave active.
    const float pr2 = fmaf((float)cr[0], dq, fmaf(xt, wi_r2, c_r2));
    const float pz2 = fmaf((float)cz[0], dq, fmaf(xt, wi_z2, c_z2));
    const float rg = __builtin_amdgcn_rcpf(1.0f + exp2f_hw(pr2));
    const float zg = __builtin_amdgcn_rcpf(1.0f + exp2f_hw(pz2));
    const float pn2 = fmaf(rg, (n0[0] + n1[0]) + bhn2, fmaf(xt, win2, bin2));
    const float ng = fmaf(-2.0f, __builtin_amdgcn_rcpf(1.0f + exp2f_hw(pn2)), 1.0f);
    h = fmaf(zg, h - ng, ng);          // z*h + (1-z)*n
    nx[w_off]  = bf16_of(h);
    nq[wq_off] = (signed char)__float2int_rn(h * 127.0f);  // |h|<1 -> fits
  };

  for (int t = 0; t < SEQ_T; t += 2) {
    step(hb[0], hq[0], hb[1], hq[1], t);
    __syncthreads();
    step(hb[1], hq[1], hb[0], hq[0], t + 1);
    __syncthreads();
  }

  // epilogue: logits = h @ Wfc^T + bfc (fp32), 4 rows x 10 outs
  hfin[quad][j] = h;
  __syncthreads();
  if (tid < 40) {
    const int r = tid / 10, o = tid - r * 10;
    float acc = bfc[o];
    #pragma unroll 4
    for (int k = 0; k < HID; ++k)
      acc = fmaf(hfin[r][k], Wfc[o * HID + k], acc);
    out[(size_t)(b0 + r) * 10 + o] = acc;
  }
}

extern "C" void kernel_launch(void* const* d_in, const int* in_sizes, int n_in,
                              void* d_out, int out_size, void* d_ws, size_t ws_size,
                              hipStream_t stream) {
  const float* x   = (const float*)d_in[0];
  const float* Wi  = (const float*)d_in[1];
  const float* bi  = (const float*)d_in[2];
  const float* Wh  = (const float*)d_in[3];
  const float* bh  = (const float*)d_in[4];
  const float* Wfc = (const float*)d_in[5];
  const float* bfc = (const float*)d_in[6];
  hipLaunchKernelGGL(gru_hyb2, dim3(256), dim3(512), 0, stream,
                     x, Wi, bi, Wh, bh, Wfc, bfc, (float*)d_out);
}